// Round 7
// baseline (157.275 us; speedup 1.0000x reference)
//
#include <hip/hip_runtime.h>
#include <math.h>

#define B_    2
#define L_    2048
#define D_    1024
#define H_    16
#define HD_   64
#define HALF_ 128

typedef __attribute__((ext_vector_type(8))) short short8;
typedef __attribute__((ext_vector_type(4))) float f32x4;

// ---- bf16 helpers (bitwise, RNE) -----------------------------------------
__device__ __forceinline__ unsigned short f2bf(float x) {
  unsigned int u = __float_as_uint(x);
  u = (u + 0x7fffu + ((u >> 16) & 1u)) >> 16;
  return (unsigned short)u;
}

__device__ __forceinline__ void async_cp16(const unsigned short* g, unsigned short* l) {
  __builtin_amdgcn_global_load_lds(
      (const __attribute__((address_space(1))) unsigned int*)g,
      (__attribute__((address_space(3))) unsigned int*)l, 16, 0, 0);
}

// ---------------------------------------------------------------------------
// prep: fused (a) x -> bf16 round, (b) w_qkv transpose+round,
//       (c) w_out transpose+round.  (unchanged)
// ---------------------------------------------------------------------------
__device__ __forceinline__ void tr_round32(const float* __restrict__ in,
                                           unsigned short* __restrict__ hi,
                                           int N, int K, int n0, int k0,
                                           float (*t)[33], int tid) {
  {
    const int kl = tid >> 3, nl = (tid & 7) * 4;
    const float4 v = *(const float4*)&in[(size_t)(k0 + kl) * N + n0 + nl];
    t[kl][nl + 0] = v.x; t[kl][nl + 1] = v.y;
    t[kl][nl + 2] = v.z; t[kl][nl + 3] = v.w;
  }
  __syncthreads();
  {
    const int no = tid >> 3, ko = (tid & 7) * 4;
    ushort4 h;
    h.x = f2bf(t[ko + 0][no]);
    h.y = f2bf(t[ko + 1][no]);
    h.z = f2bf(t[ko + 2][no]);
    h.w = f2bf(t[ko + 3][no]);
    *(ushort4*)&hi[(size_t)(n0 + no) * K + k0 + ko] = h;
  }
}

__global__ __launch_bounds__(256) void prep(const float* __restrict__ x,
                                            unsigned short* __restrict__ x_hi,
                                            const float* __restrict__ w_qkv,
                                            unsigned short* __restrict__ wqkvT,
                                            const float* __restrict__ w_out,
                                            unsigned short* __restrict__ woutT) {
  __shared__ float t[32][33];
  const int bx = blockIdx.x, tid = threadIdx.x;
  if (bx < 4096) {
    const int i = (bx * 256 + tid) * 4;
    const float4 a = *(const float4*)&x[i];
    ushort4 h;
    h.x = f2bf(a.x); h.y = f2bf(a.y); h.z = f2bf(a.z); h.w = f2bf(a.w);
    *(ushort4*)&x_hi[i] = h;
  } else if (bx < 7168) {
    const int tb = bx - 4096;  // 96 x 32 tiles
    tr_round32(w_qkv, wqkvT, 3 * D_, D_, (tb % 96) * 32, (tb / 96) * 32, t, tid);
  } else {
    const int tb = bx - 7168;  // 32 x 32 tiles
    tr_round32(w_out, woutT, D_, D_, (tb % 32) * 32, (tb / 32) * 32, t, tid);
  }
}

// ---------------------------------------------------------------------------
// gemm_qkv v4: 128x128 tile, BK=32, 2-phase ping-pong double buffer (T3
// minimum recipe): issue tile k+1's global_load_lds BEFORE computing tile k,
// then ONE counted drain (vmcnt(0) after MFMA, latency hidden) + raw
// s_barrier per tile.  BK=32 involution swizzle chunk^((r>>1)&3) (verified
// r0-r2).  Swapped-operand MFMA + 3-way epilogue unchanged.
// LDS 2 x 16 KB (v-bounce 33792 B reuses both).  Grid 768 (3/CU).
// ---------------------------------------------------------------------------
__global__ __launch_bounds__(256, 3) void gemm_qkv(
    const unsigned short* __restrict__ Ah,
    const unsigned short* __restrict__ Bh,
    const float* __restrict__ bias,
    unsigned short* __restrict__ q_hi,
    unsigned short* __restrict__ kT,
    unsigned short* __restrict__ vTile,
    int N, int K) {
  __shared__ char smraw[33792];  // 2 bufs x 16384 | v-bounce [128][132] ushort
  const int tid  = threadIdx.x;
  const int wave = tid >> 6, lane = tid & 63;

  const int lin = blockIdx.y * gridDim.x + blockIdx.x;
  const int swz = (lin & 7) * 96 + (lin >> 3);
  const int n0 = (swz % 24) * 128, m0 = (swz / 24) * 128;

  const int wm = (wave >> 1) * 64, wn = (wave & 1) * 64;
  const int quad = lane >> 4, ln16 = lane & 15;

  // ---- staging: 4 insts/thread/tile (A: s=0,1; B: s=2,3), 1 KB per wave-inst
  const int srow   = tid >> 2;      // 0..63
  const int schunk = tid & 3;       // LDS chunk slot this thread fills
  size_t gsrc[4];
  int doff[4];
#pragma unroll
  for (int s = 0; s < 4; ++s) {
    const bool isA = s < 2;
    const int r = (s & 1) * 64 + srow;          // row within 128-row tile
    const int c = schunk ^ ((r >> 1) & 3);      // involution source chunk
    gsrc[s] = (size_t)((isA ? m0 : n0) + r) * K + c * 8;
    doff[s] = (isA ? 0 : 8192) + (s & 1) * 4096 + wave * 1024;  // + lane*16 by HW
  }

#define STAGE_QKV(bufoff, ko)                                                   \
  {                                                                             \
    async_cp16(Ah + gsrc[0] + (ko), (unsigned short*)(smraw + (bufoff) + doff[0])); \
    async_cp16(Ah + gsrc[1] + (ko), (unsigned short*)(smraw + (bufoff) + doff[1])); \
    async_cp16(Bh + gsrc[2] + (ko), (unsigned short*)(smraw + (bufoff) + doff[2])); \
    async_cp16(Bh + gsrc[3] + (ko), (unsigned short*)(smraw + (bufoff) + doff[3])); \
  }

  // ---- ds_read offsets (bytes) within a buf; BK=32 rows of 64 B ----------
  int offA[4], offB[4];
#pragma unroll
  for (int t = 0; t < 4; ++t) {
    const int r = wm + t * 16 + ln16;
    offA[t] = r * 64 + ((quad ^ ((r >> 1) & 3)) * 16);
    const int rn = wn + t * 16 + ln16;
    offB[t] = 8192 + rn * 64 + ((quad ^ ((rn >> 1) & 3)) * 16);
  }

  f32x4 acc[4][4] = {};

  // prologue: stage tile 0 into buf0, drain, barrier
  STAGE_QKV(0, 0);
  asm volatile("s_waitcnt vmcnt(0)" ::: "memory");
  __builtin_amdgcn_s_barrier();

  for (int kt = 0; kt < 32; ++kt) {
    const int cur = (kt & 1) * 16384;
    if (kt < 31) STAGE_QKV(16384 - cur, (kt + 1) * 32);  // overlap w/ compute

    const char* buf = smraw + cur;
    short8 ah[4], bh[4];
#pragma unroll
    for (int t = 0; t < 4; ++t) {
      ah[t] = *(const short8*)(buf + offA[t]);
      bh[t] = *(const short8*)(buf + offB[t]);
    }
#pragma unroll
    for (int t = 0; t < 4; ++t)
#pragma unroll
      for (int u = 0; u < 4; ++u)
        acc[t][u] = __builtin_amdgcn_mfma_f32_16x16x32_bf16(bh[u], ah[t], acc[t][u], 0, 0, 0);

    asm volatile("s_waitcnt vmcnt(0)" ::: "memory");  // next tile landed (hidden)
    __builtin_amdgcn_s_barrier();
  }
#undef STAGE_QKV

  // ---- epilogue (verified r2 mapping): m = wm+t*16+ln16 ; n = wn+u*16+quad*4+e
  const int slot = n0 >> 10;
  const int nbase = n0 & 1023;

  if (slot == 0) {
#pragma unroll
    for (int t = 0; t < 4; ++t) {
      const int m = m0 + wm + t * 16 + ln16;
#pragma unroll
      for (int u = 0; u < 4; ++u) {
        const int nl = wn + u * 16 + quad * 4;
        const float4 bq = *(const float4*)&bias[n0 + nl];
        ushort4 h;
        h.x = f2bf(acc[t][u][0] + bq.x);
        h.y = f2bf(acc[t][u][1] + bq.y);
        h.z = f2bf(acc[t][u][2] + bq.z);
        h.w = f2bf(acc[t][u][3] + bq.w);
        *(ushort4*)&q_hi[(size_t)m * 1024 + nbase + nl] = h;
      }
    }
  } else if (slot == 1) {
#pragma unroll
    for (int t = 0; t < 4; ++t) {
      const int tok = m0 + wm + t * 16 + ln16;
      const int bb = tok >> 11, j = tok & 2047;
#pragma unroll
      for (int u = 0; u < 4; ++u) {
        const int nl = wn + u * 16 + quad * 4;
        const float4 bq = *(const float4*)&bias[n0 + nl];
        const int hd = nbase + nl;
        const int hh_ = hd >> 6, dg = (hd & 63) >> 3, di = hd & 7;
        ushort4 h;
        h.x = f2bf(acc[t][u][0] + bq.x);
        h.y = f2bf(acc[t][u][1] + bq.y);
        h.z = f2bf(acc[t][u][2] + bq.z);
        h.w = f2bf(acc[t][u][3] + bq.w);
        const size_t o =
            ((((size_t)bb * 16 + hh_) * 8 + dg) * 2048 + j) * 8 + di;
        *(ushort4*)&kT[o] = h;
      }
    }
  } else {
    unsigned short* lt = (unsigned short*)smraw;
#pragma unroll
    for (int t = 0; t < 4; ++t) {
      const int ml = wm + t * 16 + ln16;
#pragma unroll
      for (int u = 0; u < 4; ++u) {
        const int nl = wn + u * 16 + quad * 4;
        const float4 bq = *(const float4*)&bias[n0 + nl];
        ushort4 h;
        h.x = f2bf(acc[t][u][0] + bq.x);
        h.y = f2bf(acc[t][u][1] + bq.y);
        h.z = f2bf(acc[t][u][2] + bq.z);
        h.w = f2bf(acc[t][u][3] + bq.w);
        *(ushort4*)&lt[ml * 132 + nl] = h;
      }
    }
    __syncthreads();
    const int jg0 = (m0 & 2047) >> 3;
    const int bb = m0 >> 11;
#pragma unroll
    for (int it = 0; it < 8; ++it) {
      const int chunk = it * 256 + tid;
      const int hd = chunk & 127, tokg = chunk >> 7;
      short8 hh;
#pragma unroll
      for (int s = 0; s < 8; ++s)
        hh[s] = (short)lt[(tokg * 8 + s) * 132 + hd];
      const size_t o =
          (((size_t)bb * 256 + jg0 + tokg) * 1024 + nbase + hd) * 8;
      *(short8*)&vTile[o] = hh;
    }
  }
}

// ---------------------------------------------------------------------------
// gemm_out v3: 128m x 64n, BK=32, same 2-phase ping-pong double buffer.
// LDS 2 x 12 KB.  Swapped-operand epilogue, float4 stores (unchanged).
// ---------------------------------------------------------------------------
__global__ __launch_bounds__(256, 2) void gemm_out(
    const unsigned short* __restrict__ Ah,
    const unsigned short* __restrict__ Bh,
    const float* __restrict__ bias,
    float* __restrict__ C,
    int N, int K) {
  __shared__ char smraw[24576];  // 2 bufs x 12288 (A 8 KB | B 4 KB)
  const int tid  = threadIdx.x;
  const int wave = tid >> 6, lane = tid & 63;

  const int lin = blockIdx.y * gridDim.x + blockIdx.x;
  const int swz = (lin & 7) * 64 + (lin >> 3);
  const int n0 = (swz % 16) * 64, m0 = (swz / 16) * 128;

  const int quad = lane >> 4, ln16 = lane & 15;
  const int wm = wave * 32;

  // staging: 3 insts/thread/tile (A: s=0,1 over 128 rows; B: s=2 over 64)
  const int srow   = tid >> 2;
  const int schunk = tid & 3;
  size_t gsrc[3];
  int doff[3];
#pragma unroll
  for (int s = 0; s < 3; ++s) {
    const bool isA = s < 2;
    const int r = (isA ? (s & 1) * 64 : 0) + srow;
    const int c = schunk ^ ((r >> 1) & 3);
    gsrc[s] = (size_t)((isA ? m0 : n0) + r) * K + c * 8;
    doff[s] = (isA ? (s & 1) * 4096 : 8192) + wave * 1024;
  }

#define STAGE_OUT(bufoff, ko)                                                   \
  {                                                                             \
    async_cp16(Ah + gsrc[0] + (ko), (unsigned short*)(smraw + (bufoff) + doff[0])); \
    async_cp16(Ah + gsrc[1] + (ko), (unsigned short*)(smraw + (bufoff) + doff[1])); \
    async_cp16(Bh + gsrc[2] + (ko), (unsigned short*)(smraw + (bufoff) + doff[2])); \
  }

  int offA[2], offB[4];
#pragma unroll
  for (int t = 0; t < 2; ++t) {
    const int r = wm + t * 16 + ln16;
    offA[t] = r * 64 + ((quad ^ ((r >> 1) & 3)) * 16);
  }
#pragma unroll
  for (int u = 0; u < 4; ++u) {
    const int rn = u * 16 + ln16;
    offB[u] = 8192 + rn * 64 + ((quad ^ ((rn >> 1) & 3)) * 16);
  }

  f32x4 acc[2][4] = {};

  STAGE_OUT(0, 0);
  asm volatile("s_waitcnt vmcnt(0)" ::: "memory");
  __builtin_amdgcn_s_barrier();

  for (int kt = 0; kt < 32; ++kt) {
    const int cur = (kt & 1) * 12288;
    if (kt < 31) STAGE_OUT(12288 - cur, (kt + 1) * 32);

    const char* buf = smraw + cur;
    short8 ah[2], bh[4];
#pragma unroll
    for (int t = 0; t < 2; ++t) ah[t] = *(const short8*)(buf + offA[t]);
#pragma unroll
    for (int u = 0; u < 4; ++u) bh[u] = *(const short8*)(buf + offB[u]);
#pragma unroll
    for (int t = 0; t < 2; ++t)
#pragma unroll
      for (int u = 0; u < 4; ++u)
        acc[t][u] = __builtin_amdgcn_mfma_f32_16x16x32_bf16(bh[u], ah[t], acc[t][u], 0, 0, 0);

    asm volatile("s_waitcnt vmcnt(0)" ::: "memory");
    __builtin_amdgcn_s_barrier();
  }
#undef STAGE_OUT

#pragma unroll
  for (int t = 0; t < 2; ++t) {
    const int m = m0 + wm + t * 16 + ln16;
#pragma unroll
    for (int u = 0; u < 4; ++u) {
      const int n = n0 + u * 16 + quad * 4;
      const float4 bq = *(const float4*)&bias[n];
      float4 o;
      o.x = acc[t][u][0] + bq.x;
      o.y = acc[t][u][1] + bq.y;
      o.z = acc[t][u][2] + bq.z;
      o.w = acc[t][u][3] + bq.w;
      *(float4*)&C[(size_t)m * N + n] = o;
    }
  }
}

// ---------------------------------------------------------------------------
// attn_mfma v3 (unchanged from r6): swapped QK^T, in-register P, TQ=64,
// XCD-pinned remap, 2-deep register prefetch, setprio around MFMA.
// ---------------------------------------------------------------------------
__global__ __launch_bounds__(256) void attn_mfma(
    const unsigned short* __restrict__ q_hi,
    const unsigned short* __restrict__ kT,
    const unsigned short* __restrict__ vTile,
    unsigned short* __restrict__ attn_h) {
  __shared__ float ob[64 * 68];  // 17408 B

  const int tid = threadIdx.x;
  const int mt  = tid >> 6, lane = tid & 63;
  const int quad = lane >> 4, ln16 = lane & 15;

  const int lin  = blockIdx.x + gridDim.x * (blockIdx.y + gridDim.y * blockIdx.z);
  const int xcd  = lin & 7, idx = lin >> 3;          // idx 0..127
  const int pair = xcd * 4 + (idx >> 5);             // 0..31
  const int i0   = (idx & 31) * 64;
  const int b    = pair >> 4, h = pair & 15;
  const int jlo  = i0 - HALF_;

  const size_t qbase =
      (size_t)(b * L_ + i0 + mt * 16 + ln16) * 1024 + h * 64 + quad * 8;
  const short8 qh0 = *(const short8*)&q_hi[qbase];
  const short8 qh1 = *(const short8*)&q_hi[qbase + 32];

  const size_t kb0 = (((size_t)b * 16 + h) * 8 + quad) * 2048 * 8;
  const size_t kb1 = (((size_t)b * 16 + h) * 8 + quad + 4) * 2048 * 8;

  const int iabs = i0 + mt * 16 + ln16;

  f32x4 o[4] = {};
  float s = 0.f;

  short8 kf[2][4], vf[2][4];
  {
    const int base = jlo;
    const int j0c = min(max(base + ln16, 0), L_ - 1);
    const int j1c = min(max(base + 16 + ln16, 0), L_ - 1);
    kf[0][0] = *(const short8*)&kT[kb0 + (size_t)j0c * 8];
    kf[0][1] = *(const short8*)&kT[kb1 + (size_t)j0c * 8];
    kf[0][2] = *(const short8*)&kT[kb0 + (size_t)j1c * 8];
    kf[0][3] = *(const short8*)&kT[kb1 + (size_t)j1c * 8];
    const int jv = min(max(base + quad * 8, 0), L_ - 8);
    const size_t vgb = ((size_t)b * 256 + (jv >> 3)) * 1024 + h * 64;
#pragma unroll
    for (int t = 0; t < 4; ++t)
      vf[0][t] = *(const short8*)&vTile[(vgb + t * 16 + ln16) * 8];
  }

#pragma unroll
  for (int c = 0; c < 10; ++c) {
    const int cur = c & 1, nxt = cur ^ 1;

    if (c < 9) {
      const int nb = jlo + (c + 1) * 32;
      const int j0c = min(max(nb + ln16, 0), L_ - 1);
      const int j1c = min(max(nb + 16 + ln16, 0), L_ - 1);
      kf[nxt][0] = *(const short8*)&kT[kb0 + (size_t)j0c * 8];
      kf[nxt][1] = *(const short8*)&kT[kb1 + (size_t)j0c * 8];
      kf[nxt][2] = *(const short8*)&kT[kb0 + (size_t)j1c * 8];
      kf[nxt][3] = *(const short8*)&kT[kb1 + (size_t)j1c * 8];
      const int jv = min(max(nb + quad * 8, 0), L_ - 8);
      const size_t vgb = ((size_t)b * 256 + (jv >> 3)) * 1024 + h * 64;
#pragma unroll
      for (int t = 0; t < 4; ++t)
        vf[nxt][t] = *(const short8*)&vTile[(vgb + t * 16 + ln16) * 8];
    }

    const int base = jlo + c * 32;

    f32x4 a0 = {}, a1 = {};
    __builtin_amdgcn_s_setprio(1);
    a0 = __builtin_amdgcn_mfma_f32_16x16x32_bf16(kf[cur][0], qh0, a0, 0, 0, 0);
    a0 = __builtin_amdgcn_mfma_f32_16x16x32_bf16(kf[cur][1], qh1, a0, 0, 0, 0);
    a1 = __builtin_amdgcn_mfma_f32_16x16x32_bf16(kf[cur][2], qh0, a1, 0, 0, 0);
    a1 = __builtin_amdgcn_mfma_f32_16x16x32_bf16(kf[cur][3], qh1, a1, 0, 0, 0);
    __builtin_amdgcn_s_setprio(0);

    unsigned int pk00, pk01, pk10, pk11;
    {
      float ev[4];
#pragma unroll
      for (int e = 0; e < 4; ++e) {
        const int jabs = base + quad * 4 + e;
        const bool ok = (jabs >= 0) && (jabs < L_) && (abs(iabs - jabs) <= HALF_);
        ev[e] = ok ? __expf(a0[e] * 0.125f) : 0.f;
        s += ev[e];
      }
      pk00 = (unsigned)f2bf(ev[0]) | ((unsigned)f2bf(ev[1]) << 16);
      pk01 = (unsigned)f2bf(ev[2]) | ((unsigned)f2bf(ev[3]) << 16);
    }
    {
      float ev[4];
#pragma unroll
      for (int e = 0; e < 4; ++e) {
        const int jabs = base + 16 + quad * 4 + e;
        const bool ok = (jabs >= 0) && (jabs < L_) && (abs(iabs - jabs) <= HALF_);
        ev[e] = ok ? __expf(a1[e] * 0.125f) : 0.f;
        s += ev[e];
      }
      pk10 = (unsigned)f2bf(ev[0]) | ((unsigned)f2bf(ev[1]) << 16);
      pk11 = (unsigned)f2bf(ev[2]) | ((unsigned)f2bf(ev[3]) << 16);
    }

    const int src0 = ((quad & 1) * 2) * 16 + ln16;
    const int src1 = src0 + 16;
    const unsigned a0w = (unsigned)__shfl((int)pk00, src0);
    const unsigned b0w = (unsigned)__shfl((int)pk10, src0);
    const unsigned a1w = (unsigned)__shfl((int)pk01, src0);
    const unsigned b1w = (unsigned)__shfl((int)pk11, src0);
    const unsigned a2w = (unsigned)__shfl((int)pk00, src1);
    const unsigned b2w = (unsigned)__shfl((int)pk10, src1);
    const unsigned a3w = (unsigned)__shfl((int)pk01, src1);
    const unsigned b3w = (unsigned)__shfl((int)pk11, src1);
    int4 wv;
    wv.x = (int)((quad < 2) ? a0w : b0w);
    wv.y = (int)((quad < 2) ? a1w : b1w);
    wv.z = (int)((quad < 2) ? a2w : b2w);
    wv.w = (int)((quad < 2) ? a3w : b3w);
    const short8 pf = *(const short8*)&wv;

    __builtin_amdgcn_s_setprio(1);
#pragma unroll
    for (int t = 0; t < 4; ++t)
      o[t] = __builtin_amdgcn_mfma_f32_16x16x32_bf16(pf, vf[cur][t], o[t], 0, 0, 0);
    __builtin_amdgcn_s_setprio(0);
  }

  s += __shfl_xor(s, 16);
  s += __shfl_xor(s, 32);
  float rinv[4];
#pragma unroll
  for (int e = 0; e < 4; ++e)
    rinv[e] = 1.f / __shfl(s, quad * 4 + e);

#pragma unroll
  for (int t = 0; t < 4; ++t)
#pragma unroll
    for (int e = 0; e < 4; ++e)
      ob[(mt * 16 + quad * 4 + e) * 68 + t * 16 + ln16] = o[t][e] * rinv[e];
  __syncthreads();
#pragma unroll
  for (int pass = 0; pass < 2; ++pass) {
    const int rr = pass * 32 + (tid >> 3), ck = tid & 7;
    const float* rp = &ob[rr * 68 + ck * 8];
    const float4 f0 = *(const float4*)&rp[0];
    const float4 f1 = *(const float4*)&rp[4];
    short8 hh;
    hh[0] = (short)f2bf(f0.x); hh[1] = (short)f2bf(f0.y);
    hh[2] = (short)f2bf(f0.z); hh[3] = (short)f2bf(f0.w);
    hh[4] = (short)f2bf(f1.x); hh[5] = (short)f2bf(f1.y);
    hh[6] = (short)f2bf(f1.z); hh[7] = (short)f2bf(f1.w);
    const size_t oo = ((size_t)(b * L_ + i0 + rr)) * 1024 + h * 64 + ck * 8;
    *(short8*)&attn_h[oo] = hh;
  }
}

// ---------------------------------------------------------------------------
extern "C" void kernel_launch(void* const* d_in, const int* in_sizes, int n_in,
                              void* d_out, int out_size, void* d_ws, size_t ws_size,
                              hipStream_t stream) {
  const float* x     = (const float*)d_in[0];
  const float* w_qkv = (const float*)d_in[1];
  const float* b_qkv = (const float*)d_in[2];
  const float* w_out = (const float*)d_in[3];
  const float* b_out = (const float*)d_in[4];
  float* out = (float*)d_out;

  const int M = B_ * L_;  // 4096

  // workspace layout (bytes), total 48 MiB:
  //   x_hi @0 (8MiB)        [dead after QKV gemm; attn_h aliases it]
  //   wqkvT @16MiB (6MiB)
  //   woutT @22MiB (2MiB)
  //   q_hi  @24MiB (8MiB)   [B*L, 1024]
  //   kT    @32MiB (8MiB)   [b][h][dg8][j2048][8d]
  //   vTile @40MiB (8MiB)   [b][jg256][d1024][8j]
  char* ws = (char*)d_ws;
  unsigned short* x_hi    = (unsigned short*)(ws + 0);
  unsigned short* wqkvT   = (unsigned short*)(ws + 16777216);
  unsigned short* woutT   = (unsigned short*)(ws + 23068672);
  unsigned short* q_hi    = (unsigned short*)(ws + 25165824);
  unsigned short* kT      = (unsigned short*)(ws + 33554432);
  unsigned short* vTile   = (unsigned short*)(ws + 41943040);
  unsigned short* attn_hi = (unsigned short*)(ws + 0);

  // 1) fused prep: x round + both weight transposes
  prep<<<8192, 256, 0, stream>>>(x, x_hi, w_qkv, wqkvT, w_out, woutT);
  // 2) fused QKV projection (2-phase ping-pong pipeline) -> q_hi/kT/vTile
  {
    dim3 g(3072 / 128, M / 128);  // 768 blocks = 3/CU
    gemm_qkv<<<g, 256, 0, stream>>>(x_hi, wqkvT, b_qkv, q_hi, kT, vTile,
                                    3072, D_);
  }
  // 3) banded attention v3 -> attn_h bf16
  {
    dim3 g(L_ / 64, H_, B_);  // 1024 blocks
    attn_mfma<<<g, 256, 0, stream>>>(q_hi, kT, vTile, attn_hi);
  }
  // 4) output projection (2-phase ping-pong pipeline) -> fp32 d_out
  {
    dim3 g(D_ / 64, M / 128);  // 512 blocks
    gemm_out<<<g, 256, 0, stream>>>(attn_hi, woutT, b_out, out, D_, D_);
  }
}

// Round 9
// 155.119 us; speedup vs baseline: 1.0139x; 1.0139x over previous
//
#include <hip/hip_runtime.h>
#include <math.h>

#define B_    2
#define L_    2048
#define D_    1024
#define H_    16
#define HD_   64
#define HALF_ 128

typedef __attribute__((ext_vector_type(8))) short short8;
typedef __attribute__((ext_vector_type(4))) float f32x4;

// ---- bf16 helpers (bitwise, RNE) -----------------------------------------
__device__ __forceinline__ unsigned short f2bf(float x) {
  unsigned int u = __float_as_uint(x);
  u = (u + 0x7fffu + ((u >> 16) & 1u)) >> 16;
  return (unsigned short)u;
}

__device__ __forceinline__ void async_cp16(const unsigned short* g, unsigned short* l) {
  __builtin_amdgcn_global_load_lds(
      (const __attribute__((address_space(1))) unsigned int*)g,
      (__attribute__((address_space(3))) unsigned int*)l, 16, 0, 0);
}

// ---------------------------------------------------------------------------
// prep: fused (a) x -> bf16 round, (b) w_qkv transpose+round,
//       (c) w_out transpose+round.
// ---------------------------------------------------------------------------
__device__ __forceinline__ void tr_round32(const float* __restrict__ in,
                                           unsigned short* __restrict__ hi,
                                           int N, int K, int n0, int k0,
                                           float (*t)[33], int tid) {
  {
    const int kl = tid >> 3, nl = (tid & 7) * 4;
    const float4 v = *(const float4*)&in[(size_t)(k0 + kl) * N + n0 + nl];
    t[kl][nl + 0] = v.x; t[kl][nl + 1] = v.y;
    t[kl][nl + 2] = v.z; t[kl][nl + 3] = v.w;
  }
  __syncthreads();
  {
    const int no = tid >> 3, ko = (tid & 7) * 4;
    ushort4 h;
    h.x = f2bf(t[ko + 0][no]);
    h.y = f2bf(t[ko + 1][no]);
    h.z = f2bf(t[ko + 2][no]);
    h.w = f2bf(t[ko + 3][no]);
    *(ushort4*)&hi[(size_t)(n0 + no) * K + k0 + ko] = h;
  }
}

__global__ __launch_bounds__(256) void prep(const float* __restrict__ x,
                                            unsigned short* __restrict__ x_hi,
                                            const float* __restrict__ w_qkv,
                                            unsigned short* __restrict__ wqkvT,
                                            const float* __restrict__ w_out,
                                            unsigned short* __restrict__ woutT) {
  __shared__ float t[32][33];
  const int bx = blockIdx.x, tid = threadIdx.x;
  if (bx < 4096) {
    const int i = (bx * 256 + tid) * 4;
    const float4 a = *(const float4*)&x[i];
    ushort4 h;
    h.x = f2bf(a.x); h.y = f2bf(a.y); h.z = f2bf(a.z); h.w = f2bf(a.w);
    *(ushort4*)&x_hi[i] = h;
  } else if (bx < 7168) {
    const int tb = bx - 4096;  // 96 x 32 tiles
    tr_round32(w_qkv, wqkvT, 3 * D_, D_, (tb % 96) * 32, (tb / 96) * 32, t, tid);
  } else {
    const int tb = bx - 7168;  // 32 x 32 tiles
    tr_round32(w_out, woutT, D_, D_, (tb % 32) * 32, (tb / 32) * 32, t, tid);
  }
}

// ---------------------------------------------------------------------------
// gemm_qkv (r4/r6 version, measured best): 128x128 tile, BK=64, 32 KB LDS,
// chunk^=(r&7) swizzle, swapped-operand MFMA, 3-way epilogue.
// Grid 768 blocks (3/CU), bijective XCD swizzle.
// ---------------------------------------------------------------------------
__global__ __launch_bounds__(256, 3) void gemm_qkv(
    const unsigned short* __restrict__ Ah,
    const unsigned short* __restrict__ Bh,
    const float* __restrict__ bias,
    unsigned short* __restrict__ q_hi,
    unsigned short* __restrict__ kT,
    unsigned short* __restrict__ vTile,
    int N, int K) {
  __shared__ char smraw[33792];
  const int tid  = threadIdx.x;
  const int wave = tid >> 6, lane = tid & 63;

  const int lin = blockIdx.y * gridDim.x + blockIdx.x;
  const int swz = (lin & 7) * 96 + (lin >> 3);
  const int n0 = (swz % 24) * 128, m0 = (swz / 24) * 128;

  const int wm = (wave >> 1) * 64, wn = (wave & 1) * 64;
  const int quad = lane >> 4, ln16 = lane & 15;

  const bool isA = wave < 2;
  const unsigned short* src = isA ? Ah : Bh;
  const int baserow = isA ? m0 : n0;
  const int instbase = (wave & 1) * 8;
  const int dbase = (isA ? 0 : 16384) + instbase * 1024;
  size_t goff[8];
#pragma unroll
  for (int i = 0; i < 8; ++i) {
    const int r = (instbase + i) * 8 + (lane >> 3);
    const int c = (lane & 7) ^ (r & 7);
    goff[i] = (size_t)(baserow + r) * K + c * 8;
  }

  int offA[4], offB[4];
#pragma unroll
  for (int t = 0; t < 4; ++t) {
    const int r = wm + t * 16 + ln16;
    offA[t] = r * 128 + ((quad ^ (r & 7)) * 16);
    const int rn = wn + t * 16 + ln16;
    offB[t] = 16384 + rn * 128 + ((quad ^ (rn & 7)) * 16);
  }

  f32x4 acc[4][4] = {};
  const char* smb = (const char*)smraw;

  for (int k0 = 0; k0 < K; k0 += 64) {
#pragma unroll
    for (int i = 0; i < 8; ++i)
      async_cp16(src + goff[i] + k0,
                 (unsigned short*)(smraw + dbase + i * 1024));
    __syncthreads();

    {
      short8 ah[4], bh[4];
#pragma unroll
      for (int t = 0; t < 4; ++t) {
        ah[t] = *(const short8*)(smb + offA[t]);
        bh[t] = *(const short8*)(smb + offB[t]);
      }
#pragma unroll
      for (int t = 0; t < 4; ++t)
#pragma unroll
        for (int u = 0; u < 4; ++u)
          acc[t][u] = __builtin_amdgcn_mfma_f32_16x16x32_bf16(bh[u], ah[t], acc[t][u], 0, 0, 0);
    }
    {
      short8 ah[4], bh[4];
#pragma unroll
      for (int t = 0; t < 4; ++t) {
        ah[t] = *(const short8*)(smb + (offA[t] ^ 64));
        bh[t] = *(const short8*)(smb + (offB[t] ^ 64));
      }
#pragma unroll
      for (int t = 0; t < 4; ++t)
#pragma unroll
        for (int u = 0; u < 4; ++u)
          acc[t][u] = __builtin_amdgcn_mfma_f32_16x16x32_bf16(bh[u], ah[t], acc[t][u], 0, 0, 0);
    }
    __syncthreads();
  }

  const int slot = n0 >> 10;
  const int nbase = n0 & 1023;

  if (slot == 0) {
#pragma unroll
    for (int t = 0; t < 4; ++t) {
      const int m = m0 + wm + t * 16 + ln16;
#pragma unroll
      for (int u = 0; u < 4; ++u) {
        const int nl = wn + u * 16 + quad * 4;
        const float4 bq = *(const float4*)&bias[n0 + nl];
        ushort4 h;
        h.x = f2bf(acc[t][u][0] + bq.x);
        h.y = f2bf(acc[t][u][1] + bq.y);
        h.z = f2bf(acc[t][u][2] + bq.z);
        h.w = f2bf(acc[t][u][3] + bq.w);
        *(ushort4*)&q_hi[(size_t)m * 1024 + nbase + nl] = h;
      }
    }
  } else if (slot == 1) {
#pragma unroll
    for (int t = 0; t < 4; ++t) {
      const int tok = m0 + wm + t * 16 + ln16;
      const int bb = tok >> 11, j = tok & 2047;
#pragma unroll
      for (int u = 0; u < 4; ++u) {
        const int nl = wn + u * 16 + quad * 4;
        const float4 bq = *(const float4*)&bias[n0 + nl];
        const int hd = nbase + nl;
        const int hh_ = hd >> 6, dg = (hd & 63) >> 3, di = hd & 7;
        ushort4 h;
        h.x = f2bf(acc[t][u][0] + bq.x);
        h.y = f2bf(acc[t][u][1] + bq.y);
        h.z = f2bf(acc[t][u][2] + bq.z);
        h.w = f2bf(acc[t][u][3] + bq.w);
        const size_t o =
            ((((size_t)bb * 16 + hh_) * 8 + dg) * 2048 + j) * 8 + di;
        *(ushort4*)&kT[o] = h;
      }
    }
  } else {
    unsigned short* lt = (unsigned short*)smraw;
#pragma unroll
    for (int t = 0; t < 4; ++t) {
      const int ml = wm + t * 16 + ln16;
#pragma unroll
      for (int u = 0; u < 4; ++u) {
        const int nl = wn + u * 16 + quad * 4;
        const float4 bq = *(const float4*)&bias[n0 + nl];
        ushort4 h;
        h.x = f2bf(acc[t][u][0] + bq.x);
        h.y = f2bf(acc[t][u][1] + bq.y);
        h.z = f2bf(acc[t][u][2] + bq.z);
        h.w = f2bf(acc[t][u][3] + bq.w);
        *(ushort4*)&lt[ml * 132 + nl] = h;
      }
    }
    __syncthreads();
    const int jg0 = (m0 & 2047) >> 3;
    const int bb = m0 >> 11;
#pragma unroll
    for (int it = 0; it < 8; ++it) {
      const int chunk = it * 256 + tid;
      const int hd = chunk & 127, tokg = chunk >> 7;
      short8 hh;
#pragma unroll
      for (int s = 0; s < 8; ++s)
        hh[s] = (short)lt[(tokg * 8 + s) * 132 + hd];
      const size_t o =
          (((size_t)bb * 256 + jg0 + tokg) * 1024 + nbase + hd) * 8;
      *(short8*)&vTile[o] = hh;
    }
  }
}

// ---------------------------------------------------------------------------
// gemm_out (r4/r6 version, measured best): 128m x 64n, BK=64, 24 KB LDS,
// swapped-operand epilogue, float4 stores.
// ---------------------------------------------------------------------------
__global__ __launch_bounds__(256, 2) void gemm_out(
    const unsigned short* __restrict__ Ah,
    const unsigned short* __restrict__ Bh,
    const float* __restrict__ bias,
    float* __restrict__ C,
    int N, int K) {
  __shared__ char smraw[24576];
  const int tid  = threadIdx.x;
  const int wave = tid >> 6, lane = tid & 63;

  const int lin = blockIdx.y * gridDim.x + blockIdx.x;
  const int swz = (lin & 7) * 64 + (lin >> 3);
  const int n0 = (swz % 16) * 64, m0 = (swz / 16) * 128;

  const int quad = lane >> 4, ln16 = lane & 15;
  const int wm = wave * 32;

  const unsigned short* sptr[6];
  int dstoff[6];
#pragma unroll
  for (int s = 0; s < 6; ++s) {
    const int g = wave * 6 + s;
    const bool isA = g < 16;
    const unsigned short* base = isA ? Ah : Bh;
    const int r0 = isA ? g * 8 : (g - 16) * 8;
    const int r = r0 + (lane >> 3);
    const int c = (lane & 7) ^ (r & 7);
    sptr[s] = base + (size_t)((isA ? m0 : n0) + r) * K + c * 8;
    dstoff[s] = isA ? g * 1024 : 16384 + (g - 16) * 1024;
  }

  int offA[2], offB[4];
#pragma unroll
  for (int t = 0; t < 2; ++t) {
    const int r = wm + t * 16 + ln16;
    offA[t] = r * 128 + ((quad ^ (r & 7)) * 16);
  }
#pragma unroll
  for (int u = 0; u < 4; ++u) {
    const int rn = u * 16 + ln16;
    offB[u] = 16384 + rn * 128 + ((quad ^ (rn & 7)) * 16);
  }

  f32x4 acc[2][4] = {};
  const char* smb = (const char*)smraw;

  for (int k0 = 0; k0 < K; k0 += 64) {
#pragma unroll
    for (int s = 0; s < 6; ++s)
      async_cp16(sptr[s] + k0, (unsigned short*)(smraw + dstoff[s]));
    __syncthreads();

    {
      short8 ah[2], bh[4];
#pragma unroll
      for (int t = 0; t < 2; ++t) ah[t] = *(const short8*)(smb + offA[t]);
#pragma unroll
      for (int u = 0; u < 4; ++u) bh[u] = *(const short8*)(smb + offB[u]);
#pragma unroll
      for (int t = 0; t < 2; ++t)
#pragma unroll
        for (int u = 0; u < 4; ++u)
          acc[t][u] = __builtin_amdgcn_mfma_f32_16x16x32_bf16(bh[u], ah[t], acc[t][u], 0, 0, 0);
    }
    {
      short8 ah[2], bh[4];
#pragma unroll
      for (int t = 0; t < 2; ++t) ah[t] = *(const short8*)(smb + (offA[t] ^ 64));
#pragma unroll
      for (int u = 0; u < 4; ++u) bh[u] = *(const short8*)(smb + (offB[u] ^ 64));
#pragma unroll
      for (int t = 0; t < 2; ++t)
#pragma unroll
        for (int u = 0; u < 4; ++u)
          acc[t][u] = __builtin_amdgcn_mfma_f32_16x16x32_bf16(bh[u], ah[t], acc[t][u], 0, 0, 0);
    }
    __syncthreads();
  }

#pragma unroll
  for (int t = 0; t < 2; ++t) {
    const int m = m0 + wm + t * 16 + ln16;
#pragma unroll
    for (int u = 0; u < 4; ++u) {
      const int n = n0 + u * 16 + quad * 4;
      const float4 bq = *(const float4*)&bias[n];
      float4 o;
      o.x = acc[t][u][0] + bq.x;
      o.y = acc[t][u][1] + bq.y;
      o.z = acc[t][u][2] + bq.z;
      o.w = acc[t][u][3] + bq.w;
      *(float4*)&C[(size_t)m * N + n] = o;
    }
  }
}

// ---------------------------------------------------------------------------
// attn_mfma v3 (r6 version): swapped QK^T, in-register P, TQ=64,
// XCD-pinned remap, 2-deep register prefetch, setprio around MFMA.
// ---------------------------------------------------------------------------
__global__ __launch_bounds__(256) void attn_mfma(
    const unsigned short* __restrict__ q_hi,
    const unsigned short* __restrict__ kT,
    const unsigned short* __restrict__ vTile,
    unsigned short* __restrict__ attn_h) {
  __shared__ float ob[64 * 68];  // 17408 B

  const int tid = threadIdx.x;
  const int mt  = tid >> 6, lane = tid & 63;
  const int quad = lane >> 4, ln16 = lane & 15;

  const int lin  = blockIdx.x + gridDim.x * (blockIdx.y + gridDim.y * blockIdx.z);
  const int xcd  = lin & 7, idx = lin >> 3;          // idx 0..127
  const int pair = xcd * 4 + (idx >> 5);             // 0..31
  const int i0   = (idx & 31) * 64;
  const int b    = pair >> 4, h = pair & 15;
  const int jlo  = i0 - HALF_;

  const size_t qbase =
      (size_t)(b * L_ + i0 + mt * 16 + ln16) * 1024 + h * 64 + quad * 8;
  const short8 qh0 = *(const short8*)&q_hi[qbase];
  const short8 qh1 = *(const short8*)&q_hi[qbase + 32];

  const size_t kb0 = (((size_t)b * 16 + h) * 8 + quad) * 2048 * 8;
  const size_t kb1 = (((size_t)b * 16 + h) * 8 + quad + 4) * 2048 * 8;

  const int iabs = i0 + mt * 16 + ln16;

  f32x4 o[4] = {};
  float s = 0.f;

  short8 kf[2][4], vf[2][4];
  {
    const int base = jlo;
    const int j0c = min(max(base + ln16, 0), L_ - 1);
    const int j1c = min(max(base + 16 + ln16, 0), L_ - 1);
    kf[0][0] = *(const short8*)&kT[kb0 + (size_t)j0c * 8];
    kf[0][1] = *(const short8*)&kT[kb1 + (size_t)j0c * 8];
    kf[0][2] = *(const short8*)&kT[kb0 + (size_t)j1c * 8];
    kf[0][3] = *(const short8*)&kT[kb1 + (size_t)j1c * 8];
    const int jv = min(max(base + quad * 8, 0), L_ - 8);
    const size_t vgb = ((size_t)b * 256 + (jv >> 3)) * 1024 + h * 64;
#pragma unroll
    for (int t = 0; t < 4; ++t)
      vf[0][t] = *(const short8*)&vTile[(vgb + t * 16 + ln16) * 8];
  }

#pragma unroll
  for (int c = 0; c < 10; ++c) {
    const int cur = c & 1, nxt = cur ^ 1;

    if (c < 9) {
      const int nb = jlo + (c + 1) * 32;
      const int j0c = min(max(nb + ln16, 0), L_ - 1);
      const int j1c = min(max(nb + 16 + ln16, 0), L_ - 1);
      kf[nxt][0] = *(const short8*)&kT[kb0 + (size_t)j0c * 8];
      kf[nxt][1] = *(const short8*)&kT[kb1 + (size_t)j0c * 8];
      kf[nxt][2] = *(const short8*)&kT[kb0 + (size_t)j1c * 8];
      kf[nxt][3] = *(const short8*)&kT[kb1 + (size_t)j1c * 8];
      const int jv = min(max(nb + quad * 8, 0), L_ - 8);
      const size_t vgb = ((size_t)b * 256 + (jv >> 3)) * 1024 + h * 64;
#pragma unroll
      for (int t = 0; t < 4; ++t)
        vf[nxt][t] = *(const short8*)&vTile[(vgb + t * 16 + ln16) * 8];
    }

    const int base = jlo + c * 32;

    f32x4 a0 = {}, a1 = {};
    __builtin_amdgcn_s_setprio(1);
    a0 = __builtin_amdgcn_mfma_f32_16x16x32_bf16(kf[cur][0], qh0, a0, 0, 0, 0);
    a0 = __builtin_amdgcn_mfma_f32_16x16x32_bf16(kf[cur][1], qh1, a0, 0, 0, 0);
    a1 = __builtin_amdgcn_mfma_f32_16x16x32_bf16(kf[cur][2], qh0, a1, 0, 0, 0);
    a1 = __builtin_amdgcn_mfma_f32_16x16x32_bf16(kf[cur][3], qh1, a1, 0, 0, 0);
    __builtin_amdgcn_s_setprio(0);

    unsigned int pk00, pk01, pk10, pk11;
    {
      float ev[4];
#pragma unroll
      for (int e = 0; e < 4; ++e) {
        const int jabs = base + quad * 4 + e;
        const bool ok = (jabs >= 0) && (jabs < L_) && (abs(iabs - jabs) <= HALF_);
        ev[e] = ok ? __expf(a0[e] * 0.125f) : 0.f;
        s += ev[e];
      }
      pk00 = (unsigned)f2bf(ev[0]) | ((unsigned)f2bf(ev[1]) << 16);
      pk01 = (unsigned)f2bf(ev[2]) | ((unsigned)f2bf(ev[3]) << 16);
    }
    {
      float ev[4];
#pragma unroll
      for (int e = 0; e < 4; ++e) {
        const int jabs = base + 16 + quad * 4 + e;
        const bool ok = (jabs >= 0) && (jabs < L_) && (abs(iabs - jabs) <= HALF_);
        ev[e] = ok ? __expf(a1[e] * 0.125f) : 0.f;
        s += ev[e];
      }
      pk10 = (unsigned)f2bf(ev[0]) | ((unsigned)f2bf(ev[1]) << 16);
      pk11 = (unsigned)f2bf(ev[2]) | ((unsigned)f2bf(ev[3]) << 16);
    }

    const int src0 = ((quad & 1) * 2) * 16 + ln16;
    const int src1 = src0 + 16;
    const unsigned a0w = (unsigned)__shfl((int)pk00, src0);
    const unsigned b0w = (unsigned)__shfl((int)pk10, src0);
    const unsigned a1w = (unsigned)__shfl((int)pk01, src0);
    const unsigned b1w = (unsigned)__shfl((int)pk11, src0);
    const unsigned a2w = (unsigned)__shfl((int)pk00, src1);
    const unsigned b2w = (unsigned)__shfl((int)pk10, src1);
    const unsigned a3w = (unsigned)__shfl((int)pk01, src1);
    const unsigned b3w = (unsigned)__shfl((int)pk11, src1);
    int4 wv;
    wv.x = (int)((quad < 2) ? a0w : b0w);
    wv.y = (int)((quad < 2) ? a1w : b1w);
    wv.z = (int)((quad < 2) ? a2w : b2w);
    wv.w = (int)((quad < 2) ? a3w : b3w);
    const short8 pf = *(const short8*)&wv;

    __builtin_amdgcn_s_setprio(1);
#pragma unroll
    for (int t = 0; t < 4; ++t)
      o[t] = __builtin_amdgcn_mfma_f32_16x16x32_bf16(pf, vf[cur][t], o[t], 0, 0, 0);
    __builtin_amdgcn_s_setprio(0);
  }

  s += __shfl_xor(s, 16);
  s += __shfl_xor(s, 32);
  float rinv[4];
#pragma unroll
  for (int e = 0; e < 4; ++e)
    rinv[e] = 1.f / __shfl(s, quad * 4 + e);

#pragma unroll
  for (int t = 0; t < 4; ++t)
#pragma unroll
    for (int e = 0; e < 4; ++e)
      ob[(mt * 16 + quad * 4 + e) * 68 + t * 16 + ln16] = o[t][e] * rinv[e];
  __syncthreads();
#pragma unroll
  for (int pass = 0; pass < 2; ++pass) {
    const int rr = pass * 32 + (tid >> 3), ck = tid & 7;
    const float* rp = &ob[rr * 68 + ck * 8];
    const float4 f0 = *(const float4*)&rp[0];
    const float4 f1 = *(const float4*)&rp[4];
    short8 hh;
    hh[0] = (short)f2bf(f0.x); hh[1] = (short)f2bf(f0.y);
    hh[2] = (short)f2bf(f0.z); hh[3] = (short)f2bf(f0.w);
    hh[4] = (short)f2bf(f1.x); hh[5] = (short)f2bf(f1.y);
    hh[6] = (short)f2bf(f1.z); hh[7] = (short)f2bf(f1.w);
    const size_t oo = ((size_t)(b * L_ + i0 + rr)) * 1024 + h * 64 + ck * 8;
    *(short8*)&attn_h[oo] = hh;
  }
}

// ---------------------------------------------------------------------------
extern "C" void kernel_launch(void* const* d_in, const int* in_sizes, int n_in,
                              void* d_out, int out_size, void* d_ws, size_t ws_size,
                              hipStream_t stream) {
  const float* x     = (const float*)d_in[0];
  const float* w_qkv = (const float*)d_in[1];
  const float* b_qkv = (const float*)d_in[2];
  const float* w_out = (const float*)d_in[3];
  const float* b_out = (const float*)d_in[4];
  float* out = (float*)d_out;

  const int M = B_ * L_;  // 4096

  // workspace layout (bytes), total 48 MiB:
  //   x_hi @0 (8MiB)        [dead after QKV gemm; attn_h aliases it]
  //   wqkvT @16MiB (6MiB)
  //   woutT @22MiB (2MiB)
  //   q_hi  @24MiB (8MiB)   [B*L, 1024]
  //   kT    @32MiB (8MiB)   [b][h][dg8][j2048][8d]
  //   vTile @40MiB (8MiB)   [b][jg256][d1024][8j]
  char* ws = (char*)d_ws;
  unsigned short* x_hi    = (unsigned short*)(ws + 0);
  unsigned short* wqkvT   = (unsigned short*)(ws + 16777216);
  unsigned short* woutT   = (unsigned short*)(ws + 23068672);
  unsigned short* q_hi    = (unsigned short*)(ws + 25165824);
  unsigned short* kT      = (unsigned short*)(ws + 33554432);
  unsigned short* vTile   = (unsigned short*)(ws + 41943040);
  unsigned short* attn_hi = (unsigned short*)(ws + 0);

  // 1) fused prep: x round + both weight transposes
  prep<<<8192, 256, 0, stream>>>(x, x_hi, w_qkv, wqkvT, w_out, woutT);
  // 2) fused QKV projection (r4 BK=64 structure) -> q_hi / kT / vTile
  {
    dim3 g(3072 / 128, M / 128);  // 768 blocks = 3/CU
    gemm_qkv<<<g, 256, 0, stream>>>(x_hi, wqkvT, b_qkv, q_hi, kT, vTile,
                                    3072, D_);
  }
  // 3) banded attention v3 -> attn_h bf16
  {
    dim3 g(L_ / 64, H_, B_);  // 1024 blocks
    attn_mfma<<<g, 256, 0, stream>>>(q_hi, kT, vTile, attn_hi);
  }
  // 4) output projection (r4 BK=64 structure) -> fp32 d_out
  {
    dim3 g(D_ / 64, M / 128);  // 512 blocks
    gemm_out<<<g, 256, 0, stream>>>(attn_hi, woutT, b_out, out, D_, D_);
  }
}